// Round 14
// baseline (223.705 us; speedup 1.0000x reference)
//
#include <hip/hip_runtime.h>

#define TOKENS 8192
#define IN_F   4096
#define OUT_F  4096

#define BM 256
#define BN 256
#define BK 64
#define NT (IN_F / BK)   // 64 K-tiles

typedef __attribute__((ext_vector_type(4))) float  f32x4;
typedef __attribute__((ext_vector_type(4))) int    i32x4;

typedef const __attribute__((address_space(1))) void gas_void;
typedef __attribute__((address_space(3))) void las_void;

// ---------------------------------------------------------------------------
// quant_x: per-token symmetric i8 quantization, row-major out (r6-verified).
// ---------------------------------------------------------------------------
__global__ __launch_bounds__(256) void quant_x_kernel(const float* __restrict__ x,
                                                      signed char* __restrict__ xq,
                                                      float* __restrict__ dx) {
    const int row  = blockIdx.x;
    const int tid  = threadIdx.x;
    const int lane = tid & 63;
    const int wv   = tid >> 6;
    const float* xr = x + (size_t)row * IN_F;

    float v[16];
#pragma unroll
    for (int k = 0; k < 4; ++k) {
        f32x4 t = *(const f32x4*)(xr + k * 1024 + tid * 4);
#pragma unroll
        for (int j = 0; j < 4; ++j) v[k * 4 + j] = t[j];
    }
    float m = 0.f;
#pragma unroll
    for (int j = 0; j < 16; ++j) m = fmaxf(m, fabsf(v[j]));
#pragma unroll
    for (int off = 32; off >= 1; off >>= 1) m = fmaxf(m, __shfl_xor(m, off));
    __shared__ float sm[4];
    if (lane == 0) sm[wv] = m;
    __syncthreads();
    m = fmaxf(fmaxf(sm[0], sm[1]), fmaxf(sm[2], sm[3]));

    const float inv = 127.0f / m;
    if (tid == 0) dx[row] = m * (1.0f / 127.0f);

    int* out = (int*)(xq + (size_t)row * IN_F);
#pragma unroll
    for (int k = 0; k < 4; ++k) {
        int p = 0;
#pragma unroll
        for (int j = 0; j < 4; ++j) {
            int q = (int)rintf(v[k * 4 + j] * inv);
            p |= (q & 0xff) << (8 * j);
        }
        out[k * 256 + tid] = p;
    }
}

// ---------------------------------------------------------------------------
// quant_w: ternary -> i8 in fragment order (r10/r11-verified).
// Granule (bn, kt, g) = 1 KiB at wq[((bn*64+kt)*16+g)*1024 + lane*16]:
//   lane = lg*16+lr holds rows o = bn*256+g*16+lr, k = kt*64+lg*16 .. +16.
// ---------------------------------------------------------------------------
__global__ __launch_bounds__(256) void quant_w_kernel(const int* __restrict__ tern,
                                                      const float* __restrict__ scales,
                                                      signed char* __restrict__ wq,
                                                      float* __restrict__ dw) {
    const int o0   = blockIdx.x << 4;
    const int tid  = threadIdx.x;
    const int lane = tid & 63;
    const int lr   = lane & 15;
    const int lg   = lane >> 4;
    const int kt0  = tid >> 6;

    const int o = o0 + lr;
    const float* sr = scales + o * 32;
    float smax = 0.f;
#pragma unroll
    for (int g = 0; g < 32; ++g) smax = fmaxf(smax, sr[g]);
    const float rs = 127.0f / smax;
    if (tid < 16) dw[o0 + tid] = smax * (1.0f / 127.0f);

    const int bn  = o0 >> 8;
    const int g16 = (o0 >> 4) & 15;
    signed char* outb = wq + ((size_t)((bn * 64) * 16 + g16) << 10) + lane * 16;

#pragma unroll
    for (int i = 0; i < 16; ++i) {
        const int kt = kt0 * 16 + i;
        const int c  = kt * 4 + lg;
        const int iq = (int)rintf(sr[c >> 3] * rs);
        const i32x4* tp = (const i32x4*)(tern + (size_t)o * IN_F + c * 16);
        i32x4 w4;
#pragma unroll
        for (int k = 0; k < 4; ++k) {
            i32x4 tt = tp[k];
            int pk = 0;
#pragma unroll
            for (int j = 0; j < 4; ++j) pk |= ((tt[j] * iq) & 0xff) << (8 * j);
            w4[k] = pk;
        }
        *(i32x4*)(outb + ((size_t)(kt * 16) << 10)) = w4;
    }
}

// ---------------------------------------------------------------------------
// C = (xq . wq^T) * dx[m] * dw[n],  i8 MFMA 16x16x64, i32 acc.
// 256x256 tile, BK=64, 8 waves (2M x 4N), per-wave 128x64, acc 128 AGPR.
// r14: A via LDS (gload_lds, triple-buffer 48 KiB, r8-verified swizzle);
//      B DIRECT global->reg frag-order (r11-verified layout), prefetched
//      one tile ahead, bA/bB double-buffer (unroll-2, rule #20).
// Body t: [VMEM block: 4 B-loads(t+1) + 2 gload_lds A(t+2)] sched_barrier(0)
//   [compute: 8 ds_read a | 4 QUADs] __syncthreads().
// The single sched_barrier pins VMEM issue at body top (r10's failure was
// the compiler sinking these to body bottom -> L2 latency at next use).
// __syncthreads' implicit vmcnt(0) drains VMEM issued ~1 body earlier: free.
// Hazards (r8 audit): a-reads of buf b complete before their wave passes
// barrier(t) (lgkm before MFMA issue, in-order); stage(t+2) into buf
// (t+2)%3 issues after barrier(t-1) released = all reads of that buf done.
// LDS/tile: 64 reads (768cy) + 16KB writes (~190cy) < MFMA 1306cy.
// ---------------------------------------------------------------------------

#define QUAD(MI0, NI0, BC)                                                     \
  do {                                                                         \
    __builtin_amdgcn_s_setprio(1);                                             \
    _Pragma("unroll") for (int mi = 0; mi < 4; ++mi)                           \
      _Pragma("unroll") for (int ni = 0; ni < 2; ++ni)                         \
          acc[(MI0)+mi][(NI0)+ni] = __builtin_amdgcn_mfma_i32_16x16x64_i8(     \
              a[(MI0)+mi], BC[(NI0)+ni], acc[(MI0)+mi][(NI0)+ni], 0, 0, 0);    \
    __builtin_amdgcn_s_setprio(0);                                             \
  } while (0)

#define LOADB(BF, T)                                                           \
  do {                                                                         \
    _Pragma("unroll") for (int ni = 0; ni < 4; ++ni)                           \
        BF[ni] = *(const i32x4*)(bF + (ni << 10) + ((size_t)(T) << 14));       \
  } while (0)

#define BODY(T, BC, BNX)                                                       \
  do {                                                                         \
    if ((T) + 1 < NT) LOADB(BNX, (T) + 1);                                     \
    if ((T) + 2 < NT) stage_tile(((T) + 2) % 3, ((T) + 2) * BK);               \
    __builtin_amdgcn_sched_barrier(0);      /* pin VMEM at body top */         \
    const int abase_ = ((T) % 3) * 16384;                                      \
    _Pragma("unroll") for (int mi = 0; mi < 8; ++mi)                           \
        a[mi] = *(const i32x4*)&As[abase_ + pA[mi]];                           \
    QUAD(0, 0, BC); QUAD(0, 2, BC); QUAD(4, 0, BC); QUAD(4, 2, BC);            \
    __syncthreads();                                                           \
  } while (0)

__global__ __launch_bounds__(512, 2) void gemm_i8_kernel(
        const signed char* __restrict__ A,
        const signed char* __restrict__ B,
        const float* __restrict__ dX,
        const float* __restrict__ dW,
        float* __restrict__ C) {
    __shared__ __align__(16) signed char As[3 * 16384];

    const int tid  = threadIdx.x;
    const int wave = tid >> 6;
    const int lane = tid & 63;
    const int wm   = wave >> 2;        // 0-1
    const int wn   = wave & 3;         // 0-3
    const int lg   = lane >> 4;        // 0-3
    const int lr   = lane & 15;        // 0-15

    // XCD swizzle, bn-grouped: XCD x owns bn {2x, 2x+1} (B panels L2-resident)
    const int bid = blockIdx.x;
    const int bn  = ((bid & 7) << 1) | (bid >> 8);   // 0..15
    const int bm  = (bid >> 3) & 31;                 // 0..31

    const size_t a_row0 = (size_t)bm * BM;
    const size_t b_row0 = (size_t)bn * BN;

    // A staging (r8-verified): unit = 8KB = 128 rows x 64B, 1x16B load/thread,
    // inverse-swizzled source (rule #21), wave-uniform linear LDS dest.
    const int sx  = (tid & 7) ^ ((tid >> 3) & 7);
    const int s_r = ((tid >> 3) << 1) | ((sx >> 2) & 1);
    const int s_c = (sx & 3) << 4;

    auto stage_half = [&](int buf, int h, int k0) {
        const signed char* src = A + (a_row0 + h * 128 + s_r) * IN_F + k0 + s_c;
        signed char* dst = As + buf * 16384 + h * 8192 + (wave << 10);
        __builtin_amdgcn_global_load_lds((gas_void*)src, (las_void*)dst, 16, 0, 0);
    };
    auto stage_tile = [&](int buf, int k0) { stage_half(buf, 0, k0); stage_half(buf, 1, k0); };

    i32x4 acc[8][4] = {};
    i32x4 a[8], bA[4], bB[4];

    auto physoff = [&](int r, int c0) {
        return ((r >> 1) << 7) + (((((r & 1) << 6) | c0) ^ (((r >> 1) & 7) << 4)));
    };
    int pA[8];
#pragma unroll
    for (int mi = 0; mi < 8; ++mi) pA[mi] = physoff(wm * 128 + mi * 16 + lr, lg << 4);

    // B fragment base: granule (bn, kt=0, g = wn*4 + ni), this lane's 16B.
    const signed char* bF = B + (((size_t)(bn * 64 * 16 + wn * 4)) << 10) + lane * 16;

    // ---- prologue: stage A tiles 0,1; load B(0); syncthreads drains all
    stage_tile(0, 0); stage_tile(1, BK);
    LOADB(bA, 0);
    __syncthreads();

    for (int tt = 0; tt < NT; tt += 2) {
        BODY(tt,     bA, bB);
        BODY(tt + 1, bB, bA);
    }

    // ---- epilogue: out = acc * dx[row] * dw[col]; C/D col=lane&15, row=lg*4+j
    float dwc[4];
#pragma unroll
    for (int ni = 0; ni < 4; ++ni) dwc[ni] = dW[b_row0 + wn * 64 + ni * 16 + lr];

    float* Cp = C + (a_row0 + wm * 128) * (size_t)OUT_F + b_row0 + wn * 64;
#pragma unroll
    for (int mi = 0; mi < 8; ++mi) {
#pragma unroll
        for (int j = 0; j < 4; ++j) {
            const int r = mi * 16 + lg * 4 + j;
            const float dxr = dX[a_row0 + wm * 128 + r];
#pragma unroll
            for (int ni = 0; ni < 4; ++ni)
                Cp[(size_t)r * OUT_F + ni * 16 + lr] =
                    (float)acc[mi][ni][j] * dxr * dwc[ni];
        }
    }
}

extern "C" void kernel_launch(void* const* d_in, const int* in_sizes, int n_in,
                              void* d_out, int out_size, void* d_ws, size_t ws_size,
                              hipStream_t stream) {
    const float* x      = (const float*)d_in[0];
    const int*   tern   = (const int*)d_in[1];
    const float* scales = (const float*)d_in[2];

    signed char* xq = (signed char*)d_ws;                  // 33.6 MB row-major
    signed char* wq = xq + (size_t)TOKENS * IN_F;          // 16.8 MB frag order
    float*       dx = (float*)(wq + (size_t)OUT_F * IN_F);
    float*       dw = dx + TOKENS;

    quant_x_kernel<<<TOKENS, 256, 0, stream>>>(x, xq, dx);
    quant_w_kernel<<<OUT_F / 16, 256, 0, stream>>>(tern, scales, wq, dw);

    dim3 grid((TOKENS / BM) * (OUT_F / BN));   // 512
    gemm_i8_kernel<<<grid, 512, 0, stream>>>(xq, wq, dx, dw, (float*)d_out);
}

// Round 15
// 189.947 us; speedup vs baseline: 1.1777x; 1.1777x over previous
//
#include <hip/hip_runtime.h>

#define TOKENS 8192
#define IN_F   4096
#define OUT_F  4096

#define BM 256
#define BN 128
#define BK 64
#define NT (IN_F / BK)   // 64 K-tiles

typedef __attribute__((ext_vector_type(4))) float  f32x4;
typedef __attribute__((ext_vector_type(4))) int    i32x4;

typedef const __attribute__((address_space(1))) void gas_void;
typedef __attribute__((address_space(3))) void las_void;

// ---------------------------------------------------------------------------
// quant_x: per-token symmetric i8 quantization (r6-verified, row-major out).
// ---------------------------------------------------------------------------
__global__ __launch_bounds__(256) void quant_x_kernel(const float* __restrict__ x,
                                                      signed char* __restrict__ xq,
                                                      float* __restrict__ dx) {
    const int row  = blockIdx.x;
    const int tid  = threadIdx.x;
    const int lane = tid & 63;
    const int wv   = tid >> 6;
    const float* xr = x + (size_t)row * IN_F;

    float v[16];
#pragma unroll
    for (int k = 0; k < 4; ++k) {
        f32x4 t = *(const f32x4*)(xr + k * 1024 + tid * 4);
#pragma unroll
        for (int j = 0; j < 4; ++j) v[k * 4 + j] = t[j];
    }
    float m = 0.f;
#pragma unroll
    for (int j = 0; j < 16; ++j) m = fmaxf(m, fabsf(v[j]));
#pragma unroll
    for (int off = 32; off >= 1; off >>= 1) m = fmaxf(m, __shfl_xor(m, off));
    __shared__ float sm[4];
    if (lane == 0) sm[wv] = m;
    __syncthreads();
    m = fmaxf(fmaxf(sm[0], sm[1]), fmaxf(sm[2], sm[3]));

    const float inv = 127.0f / m;
    if (tid == 0) dx[row] = m * (1.0f / 127.0f);

    int* out = (int*)(xq + (size_t)row * IN_F);
#pragma unroll
    for (int k = 0; k < 4; ++k) {
        int p = 0;
#pragma unroll
        for (int j = 0; j < 4; ++j) {
            int q = (int)rintf(v[k * 4 + j] * inv);
            p |= (q & 0xff) << (8 * j);
        }
        out[k * 256 + tid] = p;
    }
}

// ---------------------------------------------------------------------------
// quant_w: per-out-row integer re-scale of ternary weights (r6-verified,
// row-major out).
// ---------------------------------------------------------------------------
__global__ __launch_bounds__(256) void quant_w_kernel(const int* __restrict__ tern,
                                                      const float* __restrict__ scales,
                                                      signed char* __restrict__ wq,
                                                      float* __restrict__ dw) {
    const int o   = blockIdx.x;
    const int tid = threadIdx.x;
    const float* sr = scales + o * 32;

    float smax = 0.f;
#pragma unroll
    for (int g = 0; g < 32; ++g) smax = fmaxf(smax, sr[g]);
    if (tid == 0) dw[o] = smax * (1.0f / 127.0f);

    const int g  = tid >> 3;
    const int iq = (int)rintf(sr[g] * (127.0f / smax));

    const i32x4* tp = (const i32x4*)(tern + (size_t)o * IN_F + tid * 16);
    i32x4 out;
#pragma unroll
    for (int k = 0; k < 4; ++k) {
        i32x4 t = tp[k];
        int p = 0;
#pragma unroll
        for (int j = 0; j < 4; ++j) p |= ((t[j] * iq) & 0xff) << (8 * j);
        out[k] = p;
    }
    *(i32x4*)(wq + (size_t)o * IN_F + tid * 16) = out;
}

// ---------------------------------------------------------------------------
// C = (xq . wq^T) * dx[m] * dw[n],  i8 MFMA 16x16x64, i32 acc.
// r15: TWO INDEPENDENT BARRIER DOMAINS PER CU. 256-thread blocks (4 waves,
// 2M x 2N), block tile 256x128, per-wave 128x64 (r6/r8 wave economics:
// 12 ds_read_b128 + 128 acc AGPR; LDS 1.46 B/elem-ktile). 3-buf LDS =
// 72 KB/block -> 2 blocks/CU: block 0's LDS read burst overlaps block 1's
// MFMA burst (m114 cross-block de-phasing) — the overlap no within-block
// schedule achieved (r2..r13 all ~42%).
// Body t (r8-verified single region): gate vmcnt(6) [drains stage(t), keeps
// stage(t+1)'s 6] | barrier | 12 ds_read buf t%3 | stage(t+2) (6 gloads) |
// 4 QUADs. Hazards as r8: reads of a buf complete before their wave's
// barrier arrival; stage(t+2) targets buf read in body t-1, ordered by
// barrier(t). Layout: r8-verified row-pair swizzle, 0 conflicts.
// XCD swizzle: xcd = bid&7 owns bn in [4*xcd, 4*xcd+4) (B 2MB L2-resident);
// within-XCD bn-inner order -> 4 consecutive blocks share 1MB A-tile (L2).
// ---------------------------------------------------------------------------

#define QUAD(MI0, NI0)                                                         \
  do {                                                                         \
    __builtin_amdgcn_s_setprio(1);                                             \
    _Pragma("unroll") for (int mi = 0; mi < 4; ++mi)                           \
      _Pragma("unroll") for (int ni = 0; ni < 2; ++ni)                         \
          acc[(MI0)+mi][(NI0)+ni] = __builtin_amdgcn_mfma_i32_16x16x64_i8(     \
              a[(MI0)+mi], b[(NI0)+ni], acc[(MI0)+mi][(NI0)+ni], 0, 0, 0);     \
    __builtin_amdgcn_s_setprio(0);                                             \
  } while (0)

__global__ __launch_bounds__(256, 2) void gemm_i8_kernel(
        const signed char* __restrict__ A,
        const signed char* __restrict__ B,
        const float* __restrict__ dX,
        const float* __restrict__ dW,
        float* __restrict__ C) {
    __shared__ __align__(16) signed char As[3 * 16384];   // 3 x 256x64
    __shared__ __align__(16) signed char Bs[3 * 8192];    // 3 x 128x64

    const int tid  = threadIdx.x;
    const int wave = tid >> 6;
    const int lane = tid & 63;
    const int wm   = wave >> 1;        // 0-1
    const int wn   = wave & 1;         // 0-1
    const int lg   = lane >> 4;        // 0-3
    const int lr   = lane & 15;        // 0-15

    // XCD swizzle: grid 1024 = 32bm x 32bn; xcd owns bn range, bn-inner.
    const int bid    = blockIdx.x;
    const int xcd    = bid & 7;
    const int within = bid >> 3;                 // 0..127
    const int bn     = xcd * 4 + (within & 3);   // 0..31
    const int bm     = within >> 2;              // 0..31

    const size_t a_row0 = (size_t)bm * BM;
    const size_t b_row0 = (size_t)bn * BN;

    // staging: unit = 8KB = 128 rows x 64B; 256 thr -> 2 x 16B loads/thread.
    // phys byte u*16 (u = i*256+tid) holds logical (s_r(u), s_c(u)) via the
    // r8-verified inverse swizzle; LDS dest linear (rule #21 both-sides).
    int s_r[2], s_c[2];
#pragma unroll
    for (int i = 0; i < 2; ++i) {
        const int u  = i * 256 + tid;
        const int sx = (u & 7) ^ ((u >> 3) & 7);
        s_r[i] = ((u >> 3) << 1) | ((sx >> 2) & 1);
        s_c[i] = (sx & 3) << 4;
    }

    // which: 0/1 = A unit (rows h*128..), 2 = B unit
    auto stage_unit = [&](int buf, int which, int k0) {
        const signed char* G = (which < 2) ? A : B;
        const size_t grow0 = (which < 2) ? (a_row0 + (size_t)(which & 1) * 128) : b_row0;
        signed char* dstb = (which < 2) ? (As + buf * 16384 + (which & 1) * 8192)
                                        : (Bs + buf * 8192);
#pragma unroll
        for (int i = 0; i < 2; ++i) {
            const signed char* src = G + (grow0 + s_r[i]) * IN_F + k0 + s_c[i];
            signed char* dst = dstb + i * 4096 + (wave << 10);
            __builtin_amdgcn_global_load_lds((gas_void*)src, (las_void*)dst, 16, 0, 0);
        }
    };
    auto stage_tile = [&](int buf, int k0) {
        stage_unit(buf, 0, k0); stage_unit(buf, 1, k0); stage_unit(buf, 2, k0);
    };

    i32x4 acc[8][4] = {};
    i32x4 a[8], b[4];

    auto physoff = [&](int r, int c0) {
        return ((r >> 1) << 7) + (((((r & 1) << 6) | c0) ^ (((r >> 1) & 7) << 4)));
    };
    int pA[8], pB[4];
#pragma unroll
    for (int mi = 0; mi < 8; ++mi) pA[mi] = physoff(wm * 128 + mi * 16 + lr, lg << 4);
#pragma unroll
    for (int ni = 0; ni < 4; ++ni) pB[ni] = physoff(wn * 64 + ni * 16 + lr, lg << 4);

    // ---- prologue: stage tiles 0,1 (12 loads/thread)
    stage_tile(0, 0);
    stage_tile(1, BK);

    int cur = 0;
    for (int t = 0; t < NT; ++t) {
        // gate: drain stage(t) (oldest 6); stage(t+1)'s 6 stay in flight
        if (t + 1 < NT) {
            asm volatile("s_waitcnt vmcnt(6)" ::: "memory");
        } else {
            asm volatile("s_waitcnt vmcnt(0)" ::: "memory");
        }
        __builtin_amdgcn_sched_barrier(0);
        __builtin_amdgcn_s_barrier();    // buf cur staged; buf (t+2)%3 free
        __builtin_amdgcn_sched_barrier(0);

        const int abase = cur * 16384;
        const int bbase = cur * 8192;
        int s2 = cur + 2; if (s2 >= 3) s2 -= 3;

        // ---- ONE region: reads | staging | MFMAs (scheduler interleaves;
        // cross-block de-phasing provides the pipe overlap)
#pragma unroll
        for (int mi = 0; mi < 8; ++mi) a[mi] = *(const i32x4*)&As[abase + pA[mi]];
#pragma unroll
        for (int ni = 0; ni < 4; ++ni) b[ni] = *(const i32x4*)&Bs[bbase + pB[ni]];

        if (t + 2 < NT) stage_tile(s2, (t + 2) * BK);

        QUAD(0, 0); QUAD(0, 2); QUAD(4, 0); QUAD(4, 2);

        cur = (cur == 2) ? 0 : cur + 1;
    }

    // ---- epilogue: out = acc * dx[row] * dw[col]; C/D col=lane&15, row=lg*4+j
    float dwc[4];
#pragma unroll
    for (int ni = 0; ni < 4; ++ni) dwc[ni] = dW[b_row0 + wn * 64 + ni * 16 + lr];

    float* Cp = C + (a_row0 + wm * 128) * (size_t)OUT_F + b_row0 + wn * 64;
#pragma unroll
    for (int mi = 0; mi < 8; ++mi) {
#pragma unroll
        for (int j = 0; j < 4; ++j) {
            const int r = mi * 16 + lg * 4 + j;
            const float dxr = dX[a_row0 + wm * 128 + r];
#pragma unroll
            for (int ni = 0; ni < 4; ++ni)
                Cp[(size_t)r * OUT_F + ni * 16 + lr] =
                    (float)acc[mi][ni][j] * dxr * dwc[ni];
        }
    }
}

extern "C" void kernel_launch(void* const* d_in, const int* in_sizes, int n_in,
                              void* d_out, int out_size, void* d_ws, size_t ws_size,
                              hipStream_t stream) {
    const float* x      = (const float*)d_in[0];
    const int*   tern   = (const int*)d_in[1];
    const float* scales = (const float*)d_in[2];

    signed char* xq = (signed char*)d_ws;
    signed char* wq = xq + (size_t)TOKENS * IN_F;
    float*       dx = (float*)(wq + (size_t)OUT_F * IN_F);
    float*       dw = dx + TOKENS;

    quant_x_kernel<<<TOKENS, 256, 0, stream>>>(x, xq, dx);
    quant_w_kernel<<<OUT_F, 256, 0, stream>>>(tern, scales, wq, dw);

    dim3 grid((TOKENS / BM) * (OUT_F / BN));   // 32*32 = 1024
    gemm_i8_kernel<<<grid, 256, 0, stream>>>(xq, wq, dx, dw, (float*)d_out);
}

// Round 16
// 177.964 us; speedup vs baseline: 1.2570x; 1.0673x over previous
//
#include <hip/hip_runtime.h>

#define TOKENS 8192
#define IN_F   4096
#define OUT_F  4096

#define BM 256
#define BN 256
#define BK 128
#define NT (IN_F / BK)   // 32 K-tiles

typedef __attribute__((ext_vector_type(4))) float  f32x4;
typedef __attribute__((ext_vector_type(4))) int    i32x4;

typedef const __attribute__((address_space(1))) void gas_void;
typedef __attribute__((address_space(3))) void las_void;

// ---------------------------------------------------------------------------
// quant_x: per-token symmetric i8 quantization. One block (256 thr) per row.
// xq[r][i] = rint(x*127/amax_r), dx[r] = amax_r/127.
// ---------------------------------------------------------------------------
__global__ __launch_bounds__(256) void quant_x_kernel(const float* __restrict__ x,
                                                      signed char* __restrict__ xq,
                                                      float* __restrict__ dx) {
    const int row  = blockIdx.x;
    const int tid  = threadIdx.x;
    const int lane = tid & 63;
    const int wv   = tid >> 6;
    const float* xr = x + (size_t)row * IN_F;

    float v[16];
#pragma unroll
    for (int k = 0; k < 4; ++k) {
        f32x4 t = *(const f32x4*)(xr + k * 1024 + tid * 4);
#pragma unroll
        for (int j = 0; j < 4; ++j) v[k * 4 + j] = t[j];
    }
    float m = 0.f;
#pragma unroll
    for (int j = 0; j < 16; ++j) m = fmaxf(m, fabsf(v[j]));
#pragma unroll
    for (int off = 32; off >= 1; off >>= 1) m = fmaxf(m, __shfl_xor(m, off));
    __shared__ float sm[4];
    if (lane == 0) sm[wv] = m;
    __syncthreads();
    m = fmaxf(fmaxf(sm[0], sm[1]), fmaxf(sm[2], sm[3]));

    const float inv = 127.0f / m;
    if (tid == 0) dx[row] = m * (1.0f / 127.0f);

    int* out = (int*)(xq + (size_t)row * IN_F);
#pragma unroll
    for (int k = 0; k < 4; ++k) {
        int p = 0;
#pragma unroll
        for (int j = 0; j < 4; ++j) {
            int q = (int)rintf(v[k * 4 + j] * inv);
            p |= (q & 0xff) << (8 * j);
        }
        out[k * 256 + tid] = p;
    }
}

// ---------------------------------------------------------------------------
// quant_w: per-out-row integer re-scale of ternary weights.
// s_max = max_g scales[o*32+g]; q_g = rint(s_g*127/s_max); wq = tern*q_g;
// dw[o] = s_max/127.  One block per out-row; thread t -> 16 elems, group t/8.
// ---------------------------------------------------------------------------
__global__ __launch_bounds__(256) void quant_w_kernel(const int* __restrict__ tern,
                                                      const float* __restrict__ scales,
                                                      signed char* __restrict__ wq,
                                                      float* __restrict__ dw) {
    const int o   = blockIdx.x;
    const int tid = threadIdx.x;
    const float* sr = scales + o * 32;

    float smax = 0.f;
#pragma unroll
    for (int g = 0; g < 32; ++g) smax = fmaxf(smax, sr[g]);
    if (tid == 0) dw[o] = smax * (1.0f / 127.0f);

    const int g  = tid >> 3;
    const int iq = (int)rintf(sr[g] * (127.0f / smax));

    const i32x4* tp = (const i32x4*)(tern + (size_t)o * IN_F + tid * 16);
    i32x4 out;
#pragma unroll
    for (int k = 0; k < 4; ++k) {
        i32x4 t = tp[k];
        int p = 0;
#pragma unroll
        for (int j = 0; j < 4; ++j) p |= ((t[j] * iq) & 0xff) << (8 * j);
        out[k] = p;
    }
    *(i32x4*)(wq + (size_t)o * IN_F + tid * 16) = out;
}

// ---------------------------------------------------------------------------
// C[M][N] = (xq . wq^T) * dx[m] * dw[n],  i8 MFMA 16x16x64, i32 acc.
// 256x256 tile, BK=128, 8 waves (2M x 4N), per-wave 128x64.
// BEST MEASURED (round 6: GEMM 137.8us, MfmaUtil 42.9%, conflicts 0,
// total 177.8us). r5-verified two-barrier schedule; counted vmcnt(4);
// T2 both-sides swizzle (shift 4); T5 setprio.
// LDS: [2][256][128] i8 x2 = 128 KiB. Swizzle involution:
//   LDS(row,col) = G(row, col ^ ((row&7)<<4)).
// ---------------------------------------------------------------------------

#define QUAD(MI0, NI0)                                                         \
  do {                                                                         \
    __builtin_amdgcn_s_setprio(1);                                             \
    _Pragma("unroll") for (int mi = 0; mi < 4; ++mi)                           \
      _Pragma("unroll") for (int ni = 0; ni < 2; ++ni)                         \
        _Pragma("unroll") for (int kk = 0; kk < 2; ++kk)                       \
          acc[(MI0)+mi][(NI0)+ni] = __builtin_amdgcn_mfma_i32_16x16x64_i8(     \
              a[(MI0)+mi][kk], b[(NI0)+ni][kk], acc[(MI0)+mi][(NI0)+ni],0,0,0);\
    __builtin_amdgcn_s_setprio(0);                                             \
  } while (0)

__global__ __launch_bounds__(512, 2) void gemm_i8_kernel(
        const signed char* __restrict__ A,
        const signed char* __restrict__ B,
        const float* __restrict__ dX,
        const float* __restrict__ dW,
        float* __restrict__ C) {
    __shared__ __align__(16) signed char As[2 * 256 * 128];
    __shared__ __align__(16) signed char Bs[2 * 256 * 128];

    const int tid  = threadIdx.x;
    const int wave = tid >> 6;
    const int lane = tid & 63;
    const int wm   = wave >> 2;        // 0-1
    const int wn   = wave & 3;         // 0-3
    const int lg   = lane >> 4;        // 0-3
    const int lr   = lane & 15;        // 0-15

    int bid = blockIdx.x;
    bid = (bid & 7) * (512 >> 3) + (bid >> 3);   // XCD swizzle, 512%8==0
    const int bm = bid >> 4;           // 0-31
    const int bn = bid & 15;           // 0-15

    const size_t a_row0 = (size_t)bm * BM;
    const size_t b_row0 = (size_t)bn * BN;

    // stage one half-tile (128 rows x 128 i8 = 16 KiB): 2 loads/thread.
    auto stage_half = [&](int buf, int half, int which, int k0) {
        const signed char* G = which ? B : A;
        const size_t grow0 = (which ? b_row0 : a_row0) + (size_t)half * 128;
        signed char* T = (which ? Bs : As) + buf * 32768 + half * 16384;
#pragma unroll
        for (int i = 0; i < 2; ++i) {
            const int qe    = (i * 512 + tid) * 16;         // byte offset in half
            const int row_h = qe >> 7;                      // 0..127
            const int cswz  = (qe & 127) ^ ((row_h & 7) << 4);
            const signed char* src = G + (grow0 + row_h) * IN_F + k0 + cswz;
            signed char* dst = T + i * 8192 + wave * 1024;  // wave-uniform base
            __builtin_amdgcn_global_load_lds((gas_void*)src, (las_void*)dst, 16, 0, 0);
        }
    };

    i32x4 acc[8][4] = {};
    i32x4 a[8][2], b[4][2];

    const int sw16 = (lr & 7) << 4;
    const int arow = (wm * 128 + lr) * 128;
    const int brow = (wn * 64  + lr) * 128;

    auto rdA = [&](int mi, int base) {
        a[mi][0] = *(const i32x4*)&As[base + arow + mi * 2048 + ((lg * 16) ^ sw16)];
        a[mi][1] = *(const i32x4*)&As[base + arow + mi * 2048 + ((64 + lg * 16) ^ sw16)];
    };
    auto rdB = [&](int ni, int base) {
        b[ni][0] = *(const i32x4*)&Bs[base + brow + ni * 2048 + ((lg * 16) ^ sw16)];
        b[ni][1] = *(const i32x4*)&Bs[base + brow + ni * 2048 + ((64 + lg * 16) ^ sw16)];
    };

    // ---- prologue: tile0 fully + tile1 A-halves; drain tile0, keep 4 in flight
    stage_half(0, 0, 0, 0);  stage_half(0, 1, 0, 0);
    stage_half(0, 0, 1, 0);  stage_half(0, 1, 1, 0);
    stage_half(1, 0, 0, BK); stage_half(1, 1, 0, BK);
    asm volatile("s_waitcnt vmcnt(4)" ::: "memory");
    __builtin_amdgcn_sched_barrier(0);
    __builtin_amdgcn_s_barrier();
    __builtin_amdgcn_sched_barrier(0);

    for (int t = 0; t < NT; ++t) {
        const int buf  = t & 1;
        const int base = buf * 32768;
        const int bufn = buf ^ 1;

        // ---- Region 1: all ds_reads of buf t + B-staging of t+1, QUADs 1-2.
        rdA(0, base); rdA(1, base); rdA(2, base); rdA(3, base);
        rdB(0, base); rdB(1, base);
        if (t + 1 < NT) stage_half(bufn, 0, 1, (t + 1) * BK);
        QUAD(0, 0);

        rdA(4, base); rdA(5, base); rdA(6, base); rdA(7, base);
        if (t + 1 < NT) stage_half(bufn, 1, 1, (t + 1) * BK);
        QUAD(4, 0);

        rdB(2, base); rdB(3, base);
        __builtin_amdgcn_sched_barrier(0);
        __builtin_amdgcn_s_barrier();                  // #1: As[cur] reads done
        __builtin_amdgcn_sched_barrier(0);

        // ---- Region 2: A-staging of t+2 into freed As[cur], QUADs 3-4.
        if (t + 2 < NT) stage_half(buf, 0, 0, (t + 2) * BK);
        QUAD(4, 2);
        if (t + 2 < NT) stage_half(buf, 1, 0, (t + 2) * BK);
        QUAD(0, 2);

        if (t + 2 < NT) {
            asm volatile("s_waitcnt vmcnt(4)" ::: "memory");
        } else if (t + 1 < NT) {
            asm volatile("s_waitcnt vmcnt(0)" ::: "memory");
        }
        __builtin_amdgcn_sched_barrier(0);
        __builtin_amdgcn_s_barrier();                  // #2: staged halves visible
        __builtin_amdgcn_sched_barrier(0);
    }

    // ---- epilogue: out = acc * dx[row] * dw[col]; C/D layout col=lane&15,
    // row=(lane>>4)*4+j (dtype-independent, i8-verified m121-128)
    float dwc[4];
#pragma unroll
    for (int ni = 0; ni < 4; ++ni) dwc[ni] = dW[b_row0 + wn * 64 + ni * 16 + lr];

    float* Cp = C + (a_row0 + wm * 128) * (size_t)OUT_F + b_row0 + wn * 64;
#pragma unroll
    for (int mi = 0; mi < 8; ++mi) {
#pragma unroll
        for (int j = 0; j < 4; ++j) {
            const int r = mi * 16 + lg * 4 + j;
            const float dxr = dX[a_row0 + wm * 128 + r];
#pragma unroll
            for (int ni = 0; ni < 4; ++ni)
                Cp[(size_t)r * OUT_F + ni * 16 + lr] =
                    (float)acc[mi][ni][j] * dxr * dwc[ni];
        }
    }
}

extern "C" void kernel_launch(void* const* d_in, const int* in_sizes, int n_in,
                              void* d_out, int out_size, void* d_ws, size_t ws_size,
                              hipStream_t stream) {
    const float* x      = (const float*)d_in[0];
    const int*   tern   = (const int*)d_in[1];
    const float* scales = (const float*)d_in[2];

    signed char* xq = (signed char*)d_ws;                          // 33.6 MB
    signed char* wq = xq + (size_t)TOKENS * IN_F;                  // 16.8 MB
    float*       dx = (float*)(wq + (size_t)OUT_F * IN_F);         // 32 KB
    float*       dw = dx + TOKENS;                                 // 16 KB

    quant_x_kernel<<<TOKENS, 256, 0, stream>>>(x, xq, dx);
    quant_w_kernel<<<OUT_F, 256, 0, stream>>>(tern, scales, wq, dw);

    dim3 grid((TOKENS / BM) * (OUT_F / BN));   // 512
    gemm_i8_kernel<<<grid, 512, 0, stream>>>(xq, wq, dx, dw, (float*)d_out);
}